// Round 2
// baseline (230.834 us; speedup 1.0000x reference)
//
#include <hip/hip_runtime.h>
#include <hip/hip_bf16.h>

typedef __bf16 bf16x8 __attribute__((ext_vector_type(8)));
typedef float  f32x16 __attribute__((ext_vector_type(16)));

#define ALPHA_W 0.4f

// output layout (float elements): [out 4*256*128*128][cov 8*32*32][eigen 32*32*32]
#define OUT_MAIN 16777216
#define OUT_COV  (OUT_MAIN)
#define OUT_EIG  (OUT_MAIN + 8192)

// ws layout (float offsets)
#define WS_SX   0         // 256
#define WS_SXY  256       // 8192
#define WS_CTA  8448      // 32*1024
#define WS_CTB  41216     // 32*1024
#define WS_MUA  73984     // 1024
#define WS_MUB  75008     // 1024
#define WS_SMU  76032     // 1024
#define WS_M    77056     // 32*1024  (M = alpha*UDU + 0.6*I, per (b,g))
#define WS_T    109824    // 32*32    (t vector per (b,g))

struct LinJob {
    const float* X;              // [rows, in] fp32
    const float* Wt;             // [out, in] row-major fp32
    const float* Bi;             // [out]
    float* Y;                    // [rows, out] fp32
    int in, out, act;
};

// Generic tiny linear layer: one block per (row, 256-wide out chunk).
__global__ __launch_bounds__(256) void lin_kernel(LinJob a, LinJob b, int nb0) {
    LinJob j = (blockIdx.x < (unsigned)nb0) ? a : b;
    int bid  = (blockIdx.x < (unsigned)nb0) ? blockIdx.x : blockIdx.x - nb0;
    int obpr = j.out >> 8;          // out/256 blocks per row
    int row  = bid / obpr;
    int oc   = bid % obpr;
    __shared__ float xs[256];
    int t = threadIdx.x;
    if (t < j.in) xs[t] = j.X[row * j.in + t];
    __syncthreads();
    int o = oc * 256 + t;
    const float* wr = j.Wt + (size_t)o * j.in;
    float acc = 0.f;
    for (int i = 0; i < j.in; i += 4) {
        float4 wv = *(const float4*)(wr + i);
        acc = fmaf(wv.x, xs[i + 0], acc);
        acc = fmaf(wv.y, xs[i + 1], acc);
        acc = fmaf(wv.z, xs[i + 2], acc);
        acc = fmaf(wv.w, xs[i + 3], acc);
    }
    acc += j.Bi[o];
    if (j.act) acc = acc >= 0.f ? acc : 0.01f * acc;
    j.Y[(size_t)row * j.out + o] = acc;
}

// Per-group raw gram (Sxy) + channel sums (Sx) via MFMA (A-frag == B-frag for gram).
// fp32 input, converted to bf16 in-register; Sx summed in fp32 pre-conversion.
// grid 256 blocks: bid/32 = group, bid%32 = 2048-wide n-slice. 4 waves * 512 n each.
__global__ __launch_bounds__(256) void gram_kernel(const float* __restrict__ cA,
                                                   float* __restrict__ SX,
                                                   float* __restrict__ SXY) {
    int bid = blockIdx.x;
    int g = bid >> 5, slice = bid & 31;
    int tid = threadIdx.x;
    int w = tid >> 6, l = tid & 63;
    int col = l & 31, kq = l >> 5;
    int nbase = slice * 2048 + w * 512;       // within [0, 65536), stays inside one b
    int b = nbase >> 14;
    int hw0 = nbase & 16383;
    const float* base = cA + (((size_t)(b * 256 + g * 32 + col)) << 14) + hw0 + kq * 8;

    f32x16 acc;
    #pragma unroll
    for (int r = 0; r < 16; r++) acc[r] = 0.f;
    float s = 0.f;
    for (int it = 0; it < 32; ++it) {
        float4 f0 = *(const float4*)(base + it * 16);
        float4 f1 = *(const float4*)(base + it * 16 + 4);
        s += f0.x + f0.y + f0.z + f0.w + f1.x + f1.y + f1.z + f1.w;
        bf16x8 v;
        v[0] = (__bf16)f0.x; v[1] = (__bf16)f0.y; v[2] = (__bf16)f0.z; v[3] = (__bf16)f0.w;
        v[4] = (__bf16)f1.x; v[5] = (__bf16)f1.y; v[6] = (__bf16)f1.z; v[7] = (__bf16)f1.w;
        acc = __builtin_amdgcn_mfma_f32_32x32x16_bf16(v, v, acc, 0, 0, 0);
    }
    __shared__ float red[4][1024];
    __shared__ float sxr[4][64];
    sxr[w][l] = s;
    #pragma unroll
    for (int r = 0; r < 16; r++) {
        int i = (r & 3) + 8 * (r >> 2) + 4 * kq;   // C/D layout 32x32 (symmetric matrix)
        red[w][i * 32 + col] = acc[r];
    }
    __syncthreads();
    for (int e = tid; e < 1024; e += 256) {
        float v = red[0][e] + red[1][e] + red[2][e] + red[3][e];
        atomicAdd(&SXY[g * 1024 + e], v);
    }
    if (tid < 32) {
        float v = 0.f;
        #pragma unroll
        for (int ww = 0; ww < 4; ww++) v += sxr[ww][tid] + sxr[ww][tid + 32];
        atomicAdd(&SX[g * 32 + tid], v);
    }
}

// Small finalize: blocks 0..31 -> (b,g): D,U,eigen_s, UDU -> M, t. blocks 32..39 -> cov.
__global__ __launch_bounds__(256) void small_kernel(const float* __restrict__ CT,
                                                    const float* __restrict__ SMU,
                                                    const float* __restrict__ SX,
                                                    const float* __restrict__ SXY,
                                                    float* __restrict__ M,
                                                    float* __restrict__ T,
                                                    float* __restrict__ out) {
    int bid = blockIdx.x;
    int t = threadIdx.x;
    if (bid < 32) {
        int b = bid >> 3, g = bid & 7;
        __shared__ float sct[32 * 33], uu[32 * 33], ud[32 * 33], dinv[32];
        const float* src = CT + (size_t)(b * 8 + g) * 1024;
        for (int e = t; e < 1024; e += 256) sct[(e >> 5) * 33 + (e & 31)] = src[e];
        __syncthreads();
        if (t < 32) {
            float s = 0.f;
            for (int i = 0; i < 32; i++) { float v = sct[i * 33 + t]; s = fmaf(v, v, s); }
            dinv[t] = 1.0f / sqrtf(s);
        }
        __syncthreads();
        float* eig = out + OUT_EIG + (size_t)(g * 4 + b) * 1024;
        for (int e = t; e < 1024; e += 256) {
            int i = e >> 5, jj = e & 31;
            float u = sct[i * 33 + jj] * dinv[jj];
            uu[i * 33 + jj] = u;
            eig[e] = u;
        }
        __syncthreads();
        float* Mo = M + (size_t)(b * 8 + g) * 1024;
        for (int e = t; e < 1024; e += 256) {
            int i = e >> 5, k = e & 31;
            float s = 0.f;
            for (int jv = 0; jv < 32; jv++) s = fmaf(sct[i * 33 + jv], uu[k * 33 + jv], s);
            ud[i * 33 + k] = s;
            Mo[e] = ALPHA_W * s + (i == k ? (1.0f - ALPHA_W) : 0.0f);
        }
        __syncthreads();
        if (t < 32) {
            float s = 0.f;
            for (int k = 0; k < 32; k++)
                s = fmaf(ud[t * 33 + k], SX[g * 32 + k] * (1.0f / 65536.0f), s);
            T[(b * 8 + g) * 32 + t] = ALPHA_W * (SMU[b * 256 + g * 32 + t] - s);
        }
    } else {
        int g = bid - 32;
        float* cov = out + OUT_COV + (size_t)g * 1024;
        for (int e = t; e < 1024; e += 256) {
            int i = e >> 5, jj = e & 31;
            float mi = SX[g * 32 + i] * (1.0f / 65536.0f);
            float mj = SX[g * 32 + jj] * (1.0f / 65536.0f);
            float v = (SXY[g * 1024 + e] - 65536.0f * mi * mj) * (1.0f / 65535.0f);
            if (i == jj) v += 1e-5f;
            cov[e] = v;
        }
    }
}

// out[b, g*32+i, n] = sum_k M[i,k]*cA[b, g*32+k, n] + t[i]
// grid 1024: bid/32 = (b,g), bid%32 = 512-wide hw chunk. 8 tiles of 64 columns.
__global__ __launch_bounds__(256) void color_kernel(const float* __restrict__ cA,
                                                    const float* __restrict__ M,
                                                    const float* __restrict__ T,
                                                    float* __restrict__ out) {
    int bid = blockIdx.x;
    int bg = bid >> 5, chunk = bid & 31;
    int b = bg >> 3, g = bg & 7;
    int tid = threadIdx.x;
    int n = tid & 63, ih = tid >> 6;
    __shared__ float Ml[1024];
    __shared__ float tl[32];
    __shared__ float xs[32 * 64];
    for (int e = tid; e < 1024; e += 256) Ml[e] = M[(size_t)bg * 1024 + e];
    if (tid < 32) tl[tid] = T[bg * 32 + tid];
    size_t cbase = (((size_t)(b * 256 + g * 32)) << 14) + chunk * 512;
    int srow = tid >> 3, scol = (tid & 7) * 8;
    for (int tile = 0; tile < 8; ++tile) {
        const float* src = cA + cbase + (size_t)srow * 16384 + tile * 64 + scol;
        float4 u0 = *(const float4*)src;
        float4 u1 = *(const float4*)(src + 4);
        __syncthreads();   // previous tile's readers done (also covers Ml/tl on tile 0)
        float* xd = &xs[srow * 64 + scol];
        xd[0] = u0.x; xd[1] = u0.y; xd[2] = u0.z; xd[3] = u0.w;
        xd[4] = u1.x; xd[5] = u1.y; xd[6] = u1.z; xd[7] = u1.w;
        __syncthreads();
        float acc[8];
        #pragma unroll
        for (int i = 0; i < 8; i++) acc[i] = tl[ih * 8 + i];
        for (int k = 0; k < 32; k++) {
            float xv = xs[k * 64 + n];
            #pragma unroll
            for (int i = 0; i < 8; i++) acc[i] = fmaf(Ml[(ih * 8 + i) * 32 + k], xv, acc[i]);
        }
        float* dst = out + (((size_t)(b * 256 + g * 32 + ih * 8)) << 14)
                     + chunk * 512 + tile * 64 + n;
        #pragma unroll
        for (int i = 0; i < 8; i++) dst[(size_t)i << 14] = acc[i];
    }
}

extern "C" void kernel_launch(void* const* d_in, const int* in_sizes, int n_in,
                              void* d_out, int out_size, void* d_ws, size_t ws_size,
                              hipStream_t stream) {
    (void)in_sizes; (void)n_in; (void)out_size; (void)ws_size;
    const float* cA = (const float*)d_in[0];
    const float* sB = (const float*)d_in[1];
    const float* ctw[5] = {(const float*)d_in[3], (const float*)d_in[5], (const float*)d_in[7],
                           (const float*)d_in[9], (const float*)d_in[11]};
    const float* ctb[5] = {(const float*)d_in[4], (const float*)d_in[6], (const float*)d_in[8],
                           (const float*)d_in[10], (const float*)d_in[12]};
    const float* muw[3] = {(const float*)d_in[13], (const float*)d_in[15], (const float*)d_in[17]};
    const float* mub[3] = {(const float*)d_in[14], (const float*)d_in[16], (const float*)d_in[18]};
    float* W = (float*)d_ws;
    float* out = (float*)d_out;

    // zero the Sx/Sxy accumulators (ws is poisoned 0xAA before each call)
    hipMemsetAsync(W + WS_SX, 0, (256 + 8192) * sizeof(float), stream);

    // big reduction pass (independent of MLPs)
    gram_kernel<<<256, 256, 0, stream>>>(cA, W + WS_SX, W + WS_SXY);

    LinJob a, b;
    // L0: ct0 (s_B [32,32] -> [32,256], lrelu) + mu0 (s_B [4,256] -> [4,256], lrelu)
    a = {sB, ctw[0], ctb[0], W + WS_CTA, 32, 256, 1};
    b = {sB, muw[0], mub[0], W + WS_MUA, 256, 256, 1};
    lin_kernel<<<36, 256, 0, stream>>>(a, b, 32);
    // L1: ct1 + mu1
    a = {W + WS_CTA, ctw[1], ctb[1], W + WS_CTB, 256, 256, 1};
    b = {W + WS_MUA, muw[1], mub[1], W + WS_MUB, 256, 256, 1};
    lin_kernel<<<36, 256, 0, stream>>>(a, b, 32);
    // L2: ct2 + mu2 (mu last layer: no act)
    a = {W + WS_CTB, ctw[2], ctb[2], W + WS_CTA, 256, 256, 1};
    b = {W + WS_MUB, muw[2], mub[2], W + WS_SMU, 256, 256, 0};
    lin_kernel<<<36, 256, 0, stream>>>(a, b, 32);
    // L3: ct3
    a = {W + WS_CTA, ctw[3], ctb[3], W + WS_CTB, 256, 256, 1};
    lin_kernel<<<32, 256, 0, stream>>>(a, a, 32);
    // L4: ct4 -> [32,1024], no act
    a = {W + WS_CTB, ctw[4], ctb[4], W + WS_CTA, 256, 1024, 0};
    lin_kernel<<<128, 256, 0, stream>>>(a, a, 128);

    // finalize small matrices: eigen_s + cov to out, M/t to ws
    small_kernel<<<40, 256, 0, stream>>>(W + WS_CTA, W + WS_SMU, W + WS_SX, W + WS_SXY,
                                         W + WS_M, W + WS_T, out);

    // main colored/output pass
    color_kernel<<<1024, 256, 0, stream>>>(cA, W + WS_M, W + WS_T, out);
}